// Round 15
// baseline (71.379 us; speedup 1.0000x reference)
//
#include <hip/hip_runtime.h>
#include <math.h>

#define B_ 2
#define C_ 256
#define H_ 64
#define W_ 96
#define L_ (H_*W_)          // 6144
#define NH_ 8
#define NP_ 16
#define HD_ 32
#define NTOT (B_*L_)        // 12288
#define CO_ALL 656
#define CO_PAD 768
#define RAW_CH 400
#define LDK 72              // LDS row stride in bf16 elems (64 + 8 pad)

typedef __attribute__((ext_vector_type(8))) short short8;
typedef __attribute__((ext_vector_type(4))) float f32x4;

// ---- workspace layout (float offsets) ----
#define OFF_WALLBF 0          // 768*256 ushort = 98304 floats
#define OFF_BALL   98304      // 768 floats -> 99072
#define OFF_WOUTBF 99072      // 256*256 ushort = 32768 floats -> 131840
#define OFF_FEATT  131840     // B*L*C ushort = 1572864 floats -> 1704704
#define OFF_MEMT   1704704    // B*NH*L*HD ushort = 1572864 floats -> 3277568
#define OFF_RAW    3277568    // B*400*L floats = 4915200 -> 8192768
#define OFF_MIDT   8192768    // B*L*C ushort = 1572864 floats -> 9765632 (~39.1 MB)

__device__ __forceinline__ float sigmoidf_(float x) { return 1.f / (1.f + expf(-x)); }

__device__ __forceinline__ unsigned short f2bf(float x) {
    union { float f; unsigned int u; } v; v.f = x;
    unsigned int r = (v.u + 0x7fffu + ((v.u >> 16) & 1u)) >> 16;
    return (unsigned short)r;
}

// Fused prep: blocks [0, CO_PAD+C_) pack weights to bf16; remaining 3072 blocks
// transpose feat[b][c][l] f32 -> featT[b][l][c] bf16 (32x32 LDS tiles).
__global__ __launch_bounds__(256) void prep(
        const float* __restrict__ wv, const float* __restrict__ bv,
        const float* __restrict__ wsz, const float* __restrict__ bsz,
        const float* __restrict__ wan, const float* __restrict__ ban,
        const float* __restrict__ wat, const float* __restrict__ bat,
        const float* __restrict__ wout, const float* __restrict__ feat,
        unsigned short* __restrict__ wallbf, float* __restrict__ ball,
        unsigned short* __restrict__ woutbf, unsigned short* __restrict__ featT) {
    __shared__ unsigned short tile[32][36];
    const int bid = blockIdx.x;
    const int t = threadIdx.x;
    if (bid < CO_PAD + C_) {
        const int o = bid, c = t;
        if (o < CO_PAD) {
            float v = 0.f, bvv = 0.f;
            if (o < 256)      { v = wv [(size_t)o*C_ + c];        bvv = bv [o]; }
            else if (o < 272) { v = wsz[(size_t)(o-256)*C_ + c];  bvv = bsz[o-256]; }
            else if (o < 528) { v = wan[(size_t)(o-272)*C_ + c];  bvv = ban[o-272]; }
            else if (o < 656) { v = wat[(size_t)(o-528)*C_ + c];  bvv = bat[o-528]; }
            wallbf[(size_t)o*C_ + c] = f2bf(v);
            if (c == 0) ball[o] = (o < CO_ALL) ? bvv : 0.f;
        } else {
            int r = o - CO_PAD;
            woutbf[(size_t)r*C_ + c] = f2bf(wout[(size_t)r*C_ + c]);
        }
        return;
    }
    const int tt = bid - (CO_PAD + C_);          // 0..3071
    const int l0 = (tt % (L_/32)) * 32;
    const int c0 = ((tt / (L_/32)) & 7) * 32;
    const int b  = tt / ((L_/32) * 8);
    {
        const int c = t >> 3, l4 = (t & 7) * 4;
        float4 v = *(const float4*)(feat + ((size_t)b*C_ + c0 + c)*L_ + l0 + l4);
        tile[c][l4+0] = f2bf(v.x); tile[c][l4+1] = f2bf(v.y);
        tile[c][l4+2] = f2bf(v.z); tile[c][l4+3] = f2bf(v.w);
    }
    __syncthreads();
    {
        const int l = t >> 3, c4 = (t & 7) * 4;
        ushort4 v;
        v.x = tile[c4+0][l]; v.y = tile[c4+1][l];
        v.z = tile[c4+2][l]; v.w = tile[c4+3][l];
        *(ushort4*)(featT + ((size_t)(b*L_ + l0 + l))*C_ + c0 + c4) = v;
    }
}

// GEMM-A (MFMA), 64x64 tile, 128 threads / 2 waves, 2304 blocks (9/CU).
__global__ __launch_bounds__(128) void gemm_a_mfma(const unsigned short* __restrict__ featT,
        const unsigned short* __restrict__ wallbf, const float* __restrict__ ball,
        unsigned short* __restrict__ memT, float* __restrict__ raw) {
    __shared__ short As[64 * LDK];
    __shared__ short Bs[64 * LDK];
    const int gid = blockIdx.x;          // 2304 = 8 XCD * 288
    const int xcd = gid & 7, jj = gid >> 3;
    const int yt = xcd * 24 + jj / 12;
    const int xt = jj % 12;
    const int m0 = xt * 64;
    const int n0 = yt * 64;
    const int b  = n0 / L_, l0 = n0 % L_;
    const int tid = threadIdx.x;
    const int wave = tid >> 6, lane = tid & 63;
    const int fr = lane & 15, fg = lane >> 4;
    f32x4 acc[2][4] = {};

    const unsigned short* fT = featT + ((size_t)(b*L_ + l0)) * C_;
    const int sr = tid >> 1;
    const int sko = (tid & 1) * 32;

    for (int k0 = 0; k0 < C_; k0 += 64) {
        const short8* ga = (const short8*)(wallbf + (size_t)(m0 + sr)*C_ + k0 + sko);
        const short8* gb = (const short8*)(fT + (size_t)sr*C_ + k0 + sko);
        short* la = As + sr*LDK + sko;
        short* lb = Bs + sr*LDK + sko;
        #pragma unroll
        for (int q = 0; q < 4; ++q) {
            *(short8*)(la + q*8) = ga[q];
            *(short8*)(lb + q*8) = gb[q];
        }
        __syncthreads();
        #pragma unroll
        for (int kk = 0; kk < 64; kk += 32) {
            short8 af[2], bfm[4];
            #pragma unroll
            for (int m = 0; m < 2; ++m)
                af[m] = *(const short8*)(As + (wave*32 + m*16 + fr)*LDK + kk + fg*8);
            #pragma unroll
            for (int n = 0; n < 4; ++n)
                bfm[n] = *(const short8*)(Bs + (n*16 + fr)*LDK + kk + fg*8);
            #pragma unroll
            for (int m = 0; m < 2; ++m)
                #pragma unroll
                for (int n = 0; n < 4; ++n)
                    acc[m][n] = __builtin_amdgcn_mfma_f32_16x16x32_bf16(af[m], bfm[n], acc[m][n], 0, 0, 0);
        }
        __syncthreads();
    }

    if (m0 < 256) {  // value path: memT[b][h][l][d] bf16
        #pragma unroll
        for (int m = 0; m < 2; ++m) {
            const int ob = m0 + wave*32 + m*16 + fg*4;
            const int h = ob >> 5, d0 = ob & 31;
            const float b0 = ball[ob], b1 = ball[ob+1], b2 = ball[ob+2], b3 = ball[ob+3];
            #pragma unroll
            for (int n = 0; n < 4; ++n) {
                const int l = l0 + n*16 + fr;
                ushort4 v;
                v.x = f2bf(acc[m][n][0] + b0);
                v.y = f2bf(acc[m][n][1] + b1);
                v.z = f2bf(acc[m][n][2] + b2);
                v.w = f2bf(acc[m][n][3] + b3);
                *(ushort4*)(memT + ((size_t)(b*NH_ + h)*L_ + l)*HD_ + d0) = v;
            }
        }
    } else {         // raw path: raw[b][r][l] f32
        #pragma unroll
        for (int m = 0; m < 2; ++m) {
            const int ob = m0 + wave*32 + m*16 + fg*4;
            #pragma unroll
            for (int n = 0; n < 4; ++n) {
                const int l = l0 + n*16 + fr;
                #pragma unroll
                for (int q = 0; q < 4; ++q) {
                    const int r = ob + q - 256;
                    if (r < RAW_CH)
                        raw[((size_t)(b*RAW_CH + r))*L_ + l] = acc[m][n][q] + ball[ob+q];
                }
            }
        }
    }
}

// Fused sampling, x-half-split records.
// phase0: tbl[xh][l][p] = {o_row0, o_row1, w_row0, w_row1} — offsets clamped
// in-bounds (dup cells carry weight exactly 0). Main: lane = d4(0..7) x xh(2) x
// pg(4); per point 1 ds_read_b128 + 2 uint2 loads, no selects. Reduce xor 8/16/32;
// lanes 0-7 store 4 bf16 directly to midT. Segment count unchanged vs R11.
__global__ __launch_bounds__(256) void sample_kernel(
        const unsigned short* __restrict__ memT,
        const float* __restrict__ raw,
        unsigned short* __restrict__ midT) {
    __shared__ int4 tbl[2][16][16];
    const int blk = blockIdx.x;          // 6144 = B_*NH_*(L_/16)
    const int xcd = blk & 7;
    const int j   = blk >> 3;
    const int half = (j >= 384) ? 1 : 0;
    const int bh  = xcd * 2 + half;
    const int lt  = j - half * 384;
    const int h = bh & 7;
    const int b = bh >> 3;
    const int l0 = lt * 16;
    const int tid = threadIdx.x;

    // ---- phase 0: one finished record pair per thread (16 l x 16 p) ----
    {
        const int p    = tid & 15;
        const int lsub = tid >> 4;
        const int l = l0 + lsub;
        const float* rb = raw + (size_t)b * RAW_CH * L_ + l;
        float sx = fminf(fmaxf(sigmoidf_(rb[(h*2+0)*L_]), 0.25f), 0.75f);
        float sy = fminf(fmaxf(sigmoidf_(rb[(h*2+1)*L_]), 0.25f), 0.75f);
        float cx = ((l % W_) + 0.5f) / ((float)W_ + 1e-6f);
        float cy = ((l / W_) + 0.5f) / ((float)H_ + 1e-6f);
        float ox = sigmoidf_(rb[(16 + h*32 + p*2 + 0)*L_]);
        float oy = sigmoidf_(rb[(16 + h*32 + p*2 + 1)*L_]);
        float gx = fminf(fmaxf(cx - 0.5f*sx + ox*sx, 0.f), 1.f) * (float)(W_-1);
        float gy = fminf(fmaxf(cy - 0.5f*sy + oy*sy, 0.f), 1.f) * (float)(H_-1);
        float a = rb[(272 + h*16 + p)*L_];
        float m = a;
        #pragma unroll
        for (int dd = 8; dd >= 1; dd >>= 1) m = fmaxf(m, __shfl_xor(m, dd, 16));
        float e = expf(a - m);
        float s = e;
        #pragma unroll
        for (int dd = 8; dd >= 1; dd >>= 1) s += __shfl_xor(s, dd, 16);
        float aw = e / s;
        float x0f = floorf(gx), y0f = floorf(gy);
        int x0 = (int)x0f, y0 = (int)y0f;
        const float wx = gx - x0f, wy = gy - y0f;
        const float aiy = aw * (1.f - wy), awy = aw * wy;
        const int o00 = (y0*W_ + x0) * (HD_*2);
        const int dxb = (x0 < W_-1) ? (HD_*2) : 0;
        const int o10 = o00 + ((y0 < H_-1) ? (W_*HD_*2) : 0);
        tbl[0][lsub][p] = make_int4(o00, o10,
                                    __float_as_int(aiy * (1.f - wx)),
                                    __float_as_int(awy * (1.f - wx)));
        tbl[1][lsub][p] = make_int4(o00 + dxb, o10 + dxb,
                                    __float_as_int(aiy * wx),
                                    __float_as_int(awy * wx));
    }
    __syncthreads();

    // ---- main: per point one record read + two uint2 row loads ----
    const int wave = tid >> 6, lane = tid & 63;
    const int d4 = lane & 7;             // uint2 slot: d = d4*4 .. d4*4+3
    const int xh = (lane >> 3) & 1;      // x-half
    const int pg = lane >> 4;            // 0..3, points p = pg*4 + pi
    const int d4b = d4 * 8;              // byte offset within 64B cell
    const char* vbytes = (const char*)(memT + (size_t)(b*NH_ + h) * L_ * HD_);

    for (int li = 0; li < 4; ++li) {
        const int lsub = wave*4 + li;
        f32x4 acc = {0.f, 0.f, 0.f, 0.f};
        #pragma unroll
        for (int pi = 0; pi < 4; ++pi) {
            const int4 r = tbl[xh][lsub][pg*4 + pi];
            const uint2 u0 = *(const uint2*)(vbytes + (uint)(r.x + d4b));
            const uint2 u1 = *(const uint2*)(vbytes + (uint)(r.y + d4b));
            const float w0 = __int_as_float(r.z);
            const float w1 = __int_as_float(r.w);
            acc.x += w0 * __uint_as_float(u0.x << 16);
            acc.y += w0 * __uint_as_float(u0.x & 0xffff0000u);
            acc.z += w0 * __uint_as_float(u0.y << 16);
            acc.w += w0 * __uint_as_float(u0.y & 0xffff0000u);
            acc.x += w1 * __uint_as_float(u1.x << 16);
            acc.y += w1 * __uint_as_float(u1.x & 0xffff0000u);
            acc.z += w1 * __uint_as_float(u1.y << 16);
            acc.w += w1 * __uint_as_float(u1.y & 0xffff0000u);
        }
        #pragma unroll
        for (int s = 8; s <= 32; s <<= 1) {
            acc.x += __shfl_xor(acc.x, s);
            acc.y += __shfl_xor(acc.y, s);
            acc.z += __shfl_xor(acc.z, s);
            acc.w += __shfl_xor(acc.w, s);
        }
        if (lane < 8) {
            ushort4 v;
            v.x = f2bf(acc.x); v.y = f2bf(acc.y);
            v.z = f2bf(acc.z); v.w = f2bf(acc.w);
            *(ushort4*)(midT + ((size_t)(b*L_ + l0 + lsub))*C_ + h*HD_ + lane*4) = v;
        }
    }
}

// GEMM-B (MFMA), 64x64 tile, 128 threads / 2 waves, 768 blocks (3/CU).
__global__ __launch_bounds__(128) void gemm_b_mfma(const unsigned short* __restrict__ midT,
        const unsigned short* __restrict__ woutbf,
        const float* __restrict__ gamma, const float* __restrict__ beta,
        const float* __restrict__ mean, const float* __restrict__ var,
        float* __restrict__ out) {
    __shared__ short As[64 * LDK];
    __shared__ short Bs[64 * LDK];
    const int gid = blockIdx.x;          // 768 = 8 XCD * 96
    const int xcd = gid & 7, jj = gid >> 3;
    const int yt = xcd * 24 + jj / 4;
    const int xt = jj & 3;
    const int m0 = xt * 64;
    const int n0 = yt * 64;
    const int b  = n0 / L_, l0 = n0 % L_;
    const int tid = threadIdx.x;
    const int wave = tid >> 6, lane = tid & 63;
    const int fr = lane & 15, fg = lane >> 4;
    f32x4 acc[2][4] = {};

    const unsigned short* mT = midT + ((size_t)(b*L_ + l0)) * C_;
    const int sr = tid >> 1;
    const int sko = (tid & 1) * 32;

    for (int k0 = 0; k0 < C_; k0 += 64) {
        const short8* ga = (const short8*)(woutbf + (size_t)(m0 + sr)*C_ + k0 + sko);
        const short8* gb = (const short8*)(mT + (size_t)sr*C_ + k0 + sko);
        short* la = As + sr*LDK + sko;
        short* lb = Bs + sr*LDK + sko;
        #pragma unroll
        for (int q = 0; q < 4; ++q) {
            *(short8*)(la + q*8) = ga[q];
            *(short8*)(lb + q*8) = gb[q];
        }
        __syncthreads();
        #pragma unroll
        for (int kk = 0; kk < 64; kk += 32) {
            short8 af[2], bfm[4];
            #pragma unroll
            for (int m = 0; m < 2; ++m)
                af[m] = *(const short8*)(As + (wave*32 + m*16 + fr)*LDK + kk + fg*8);
            #pragma unroll
            for (int n = 0; n < 4; ++n)
                bfm[n] = *(const short8*)(Bs + (n*16 + fr)*LDK + kk + fg*8);
            #pragma unroll
            for (int m = 0; m < 2; ++m)
                #pragma unroll
                for (int n = 0; n < 4; ++n)
                    acc[m][n] = __builtin_amdgcn_mfma_f32_16x16x32_bf16(af[m], bfm[n], acc[m][n], 0, 0, 0);
        }
        __syncthreads();
    }

    #pragma unroll
    for (int m = 0; m < 2; ++m) {
        const int ob = m0 + wave*32 + m*16 + fg*4;
        float sc[4], mn[4], bt[4];
        #pragma unroll
        for (int q = 0; q < 4; ++q) {
            const int o = ob + q;
            sc[q] = gamma[o] * rsqrtf(var[o] + 1e-5f);
            mn[q] = mean[o]; bt[q] = beta[o];
        }
        #pragma unroll
        for (int n = 0; n < 4; ++n) {
            const int l = l0 + n*16 + fr;
            #pragma unroll
            for (int q = 0; q < 4; ++q)
                out[(size_t)b*C_*L_ + (size_t)(ob+q)*L_ + l] = (acc[m][n][q] - mn[q])*sc[q] + bt[q];
        }
    }
}

extern "C" void kernel_launch(void* const* d_in, const int* in_sizes, int n_in,
                              void* d_out, int out_size, void* d_ws, size_t ws_size,
                              hipStream_t stream) {
    const float* feat     = (const float*)d_in[0];
    const float* w_size   = (const float*)d_in[1];
    const float* b_size   = (const float*)d_in[2];
    const float* w_anchor = (const float*)d_in[3];
    const float* b_anchor = (const float*)d_in[4];
    const float* w_value  = (const float*)d_in[5];
    const float* b_value  = (const float*)d_in[6];
    const float* w_att    = (const float*)d_in[7];
    const float* b_att    = (const float*)d_in[8];
    const float* w_out    = (const float*)d_in[9];
    const float* bn_gamma = (const float*)d_in[10];
    const float* bn_beta  = (const float*)d_in[11];
    const float* bn_mean  = (const float*)d_in[12];
    const float* bn_var   = (const float*)d_in[13];

    float* ws = (float*)d_ws;
    unsigned short* wallbf = (unsigned short*)(ws + OFF_WALLBF);
    float*          ball   = ws + OFF_BALL;
    unsigned short* woutbf = (unsigned short*)(ws + OFF_WOUTBF);
    unsigned short* featT  = (unsigned short*)(ws + OFF_FEATT);
    unsigned short* memT   = (unsigned short*)(ws + OFF_MEMT);
    float*          raw    = ws + OFF_RAW;
    unsigned short* midT   = (unsigned short*)(ws + OFF_MIDT);

    prep<<<dim3(CO_PAD + C_ + (L_/32)*8*B_), dim3(256), 0, stream>>>(
        w_value, b_value, w_size, b_size, w_anchor, b_anchor, w_att, b_att,
        w_out, feat, wallbf, ball, woutbf, featT);
    gemm_a_mfma<<<dim3(8*288), dim3(128), 0, stream>>>(featT, wallbf, ball, memT, raw);
    sample_kernel<<<dim3(B_*NH_*(L_/16)), dim3(256), 0, stream>>>(memT, raw, midT);
    gemm_b_mfma<<<dim3(8*96), dim3(128), 0, stream>>>(
        midT, woutbf, bn_gamma, bn_beta, bn_mean, bn_var, (float*)d_out);
}

// Round 16
// 62.756 us; speedup vs baseline: 1.1374x; 1.1374x over previous
//
#include <hip/hip_runtime.h>
#include <math.h>

#define B_ 2
#define C_ 256
#define H_ 64
#define W_ 96
#define L_ (H_*W_)          // 6144
#define NH_ 8
#define NP_ 16
#define HD_ 32
#define NTOT (B_*L_)        // 12288
#define CO_ALL 656
#define CO_PAD 768
#define RAW_CH 400
#define LDK 72              // LDS row stride in bf16 elems (64 + 8 pad)

typedef __attribute__((ext_vector_type(8))) short short8;
typedef __attribute__((ext_vector_type(4))) float f32x4;
typedef __attribute__((ext_vector_type(2))) float f32x2;

// ---- workspace layout (float offsets) ----
#define OFF_WALLBF 0          // 768*256 ushort = 98304 floats
#define OFF_BALL   98304      // 768 floats -> 99072
#define OFF_WOUTBF 99072      // 256*256 ushort = 32768 floats -> 131840
#define OFF_FEATT  131840     // B*L*C ushort = 1572864 floats -> 1704704
#define OFF_MEMT   1704704    // B*NH*L*HD ushort = 1572864 floats -> 3277568
#define OFF_RAW    3277568    // B*400*L floats = 4915200 -> 8192768
#define OFF_MIDT   8192768    // B*L*C ushort = 1572864 floats -> 9765632 (~39.1 MB)

__device__ __forceinline__ float sigmoidf_(float x) { return 1.f / (1.f + expf(-x)); }

__device__ __forceinline__ unsigned short f2bf(float x) {
    union { float f; unsigned int u; } v; v.f = x;
    unsigned int r = (v.u + 0x7fffu + ((v.u >> 16) & 1u)) >> 16;
    return (unsigned short)r;
}

// Fused prep: blocks [0, CO_PAD+C_) pack weights to bf16; remaining 3072 blocks
// transpose feat[b][c][l] f32 -> featT[b][l][c] bf16 (32x32 LDS tiles).
__global__ __launch_bounds__(256) void prep(
        const float* __restrict__ wv, const float* __restrict__ bv,
        const float* __restrict__ wsz, const float* __restrict__ bsz,
        const float* __restrict__ wan, const float* __restrict__ ban,
        const float* __restrict__ wat, const float* __restrict__ bat,
        const float* __restrict__ wout, const float* __restrict__ feat,
        unsigned short* __restrict__ wallbf, float* __restrict__ ball,
        unsigned short* __restrict__ woutbf, unsigned short* __restrict__ featT) {
    __shared__ unsigned short tile[32][36];
    const int bid = blockIdx.x;
    const int t = threadIdx.x;
    if (bid < CO_PAD + C_) {
        const int o = bid, c = t;
        if (o < CO_PAD) {
            float v = 0.f, bvv = 0.f;
            if (o < 256)      { v = wv [(size_t)o*C_ + c];        bvv = bv [o]; }
            else if (o < 272) { v = wsz[(size_t)(o-256)*C_ + c];  bvv = bsz[o-256]; }
            else if (o < 528) { v = wan[(size_t)(o-272)*C_ + c];  bvv = ban[o-272]; }
            else if (o < 656) { v = wat[(size_t)(o-528)*C_ + c];  bvv = bat[o-528]; }
            wallbf[(size_t)o*C_ + c] = f2bf(v);
            if (c == 0) ball[o] = (o < CO_ALL) ? bvv : 0.f;
        } else {
            int r = o - CO_PAD;
            woutbf[(size_t)r*C_ + c] = f2bf(wout[(size_t)r*C_ + c]);
        }
        return;
    }
    const int tt = bid - (CO_PAD + C_);          // 0..3071
    const int l0 = (tt % (L_/32)) * 32;
    const int c0 = ((tt / (L_/32)) & 7) * 32;
    const int b  = tt / ((L_/32) * 8);
    {
        const int c = t >> 3, l4 = (t & 7) * 4;
        float4 v = *(const float4*)(feat + ((size_t)b*C_ + c0 + c)*L_ + l0 + l4);
        tile[c][l4+0] = f2bf(v.x); tile[c][l4+1] = f2bf(v.y);
        tile[c][l4+2] = f2bf(v.z); tile[c][l4+3] = f2bf(v.w);
    }
    __syncthreads();
    {
        const int l = t >> 3, c4 = (t & 7) * 4;
        ushort4 v;
        v.x = tile[c4+0][l]; v.y = tile[c4+1][l];
        v.z = tile[c4+2][l]; v.w = tile[c4+3][l];
        *(ushort4*)(featT + ((size_t)(b*L_ + l0 + l))*C_ + c0 + c4) = v;
    }
}

// GEMM-A (MFMA), 64x64 tile, 128 threads / 2 waves, 2304 blocks (9/CU).
// y[b,o,l] = ball[o] + sum_c wall[o,c]*feat[b,c,l]
// o<256 -> memT[b][h][l][d] bf16 ; o in [256,656) -> raw[b][o-256][l] f32
__global__ __launch_bounds__(128) void gemm_a_mfma(const unsigned short* __restrict__ featT,
        const unsigned short* __restrict__ wallbf, const float* __restrict__ ball,
        unsigned short* __restrict__ memT, float* __restrict__ raw) {
    __shared__ short As[64 * LDK];
    __shared__ short Bs[64 * LDK];
    const int gid = blockIdx.x;          // 2304 = 8 XCD * 288
    const int xcd = gid & 7, jj = gid >> 3;   // jj 0..287
    const int yt = xcd * 24 + jj / 12;   // n-tile 0..191 (contiguous l per XCD)
    const int xt = jj % 12;              // m-tile 0..11
    const int m0 = xt * 64;
    const int n0 = yt * 64;
    const int b  = n0 / L_, l0 = n0 % L_;
    const int tid = threadIdx.x;
    const int wave = tid >> 6, lane = tid & 63;
    const int fr = lane & 15, fg = lane >> 4;
    f32x4 acc[2][4] = {};

    const unsigned short* fT = featT + ((size_t)(b*L_ + l0)) * C_;
    const int sr = tid >> 1;             // staging row 0..63
    const int sko = (tid & 1) * 32;      // k offset 0/32

    for (int k0 = 0; k0 < C_; k0 += 64) {
        const short8* ga = (const short8*)(wallbf + (size_t)(m0 + sr)*C_ + k0 + sko);
        const short8* gb = (const short8*)(fT + (size_t)sr*C_ + k0 + sko);
        short* la = As + sr*LDK + sko;
        short* lb = Bs + sr*LDK + sko;
        #pragma unroll
        for (int q = 0; q < 4; ++q) {
            *(short8*)(la + q*8) = ga[q];
            *(short8*)(lb + q*8) = gb[q];
        }
        __syncthreads();
        #pragma unroll
        for (int kk = 0; kk < 64; kk += 32) {
            short8 af[2], bfm[4];
            #pragma unroll
            for (int m = 0; m < 2; ++m)
                af[m] = *(const short8*)(As + (wave*32 + m*16 + fr)*LDK + kk + fg*8);
            #pragma unroll
            for (int n = 0; n < 4; ++n)
                bfm[n] = *(const short8*)(Bs + (n*16 + fr)*LDK + kk + fg*8);
            #pragma unroll
            for (int m = 0; m < 2; ++m)
                #pragma unroll
                for (int n = 0; n < 4; ++n)
                    acc[m][n] = __builtin_amdgcn_mfma_f32_16x16x32_bf16(af[m], bfm[n], acc[m][n], 0, 0, 0);
        }
        __syncthreads();
    }

    if (m0 < 256) {  // value path: memT[b][h][l][d] bf16
        #pragma unroll
        for (int m = 0; m < 2; ++m) {
            const int ob = m0 + wave*32 + m*16 + fg*4;
            const int h = ob >> 5, d0 = ob & 31;
            const float b0 = ball[ob], b1 = ball[ob+1], b2 = ball[ob+2], b3 = ball[ob+3];
            #pragma unroll
            for (int n = 0; n < 4; ++n) {
                const int l = l0 + n*16 + fr;
                ushort4 v;
                v.x = f2bf(acc[m][n][0] + b0);
                v.y = f2bf(acc[m][n][1] + b1);
                v.z = f2bf(acc[m][n][2] + b2);
                v.w = f2bf(acc[m][n][3] + b3);
                *(ushort4*)(memT + ((size_t)(b*NH_ + h)*L_ + l)*HD_ + d0) = v;
            }
        }
    } else {         // raw path: raw[b][r][l] f32
        #pragma unroll
        for (int m = 0; m < 2; ++m) {
            const int ob = m0 + wave*32 + m*16 + fg*4;
            #pragma unroll
            for (int n = 0; n < 4; ++n) {
                const int l = l0 + n*16 + fr;
                #pragma unroll
                for (int q = 0; q < 4; ++q) {
                    const int r = ob + q - 256;
                    if (r < RAW_CH)
                        raw[((size_t)(b*RAW_CH + r))*L_ + l] = acc[m][n][q] + ball[ob+q];
                }
            }
        }
    }
}

// Fused sampling (exact R11 structure — best verified).
// phase0 precomputes finished per-(l,p) records: tblo = 4 clamped byte-offsets,
// tblw = 4 combined bilinear*attention weights. Main: 16 d2-lanes x 4 pgs,
// 16 saddr dword loads per l-iter, pk-FMA, xor-16/32 reduce, LDS tile epilogue.
__global__ __launch_bounds__(256) void sample_kernel(
        const unsigned short* __restrict__ memT,
        const float* __restrict__ raw,
        unsigned short* __restrict__ midT) {
    __shared__ int4   tblo[16][16];
    __shared__ float4 tblw[16][16];
    __shared__ float  tile[16][33];
    const int blk = blockIdx.x;          // 6144 = B_*NH_*(L_/16)
    const int xcd = blk & 7;
    const int j   = blk >> 3;
    const int half = (j >= 384) ? 1 : 0;
    const int bh  = xcd * 2 + half;
    const int lt  = j - half * 384;
    const int h = bh & 7;
    const int b = bh >> 3;
    const int l0 = lt * 16;
    const int tid = threadIdx.x;

    // ---- phase 0: one finished record per thread (16 l x 16 p) ----
    {
        const int p    = tid & 15;
        const int lsub = tid >> 4;
        const int l = l0 + lsub;
        const float* rb = raw + (size_t)b * RAW_CH * L_ + l;
        float sx = fminf(fmaxf(sigmoidf_(rb[(h*2+0)*L_]), 0.25f), 0.75f);
        float sy = fminf(fmaxf(sigmoidf_(rb[(h*2+1)*L_]), 0.25f), 0.75f);
        float cx = ((l % W_) + 0.5f) / ((float)W_ + 1e-6f);
        float cy = ((l / W_) + 0.5f) / ((float)H_ + 1e-6f);
        float ox = sigmoidf_(rb[(16 + h*32 + p*2 + 0)*L_]);
        float oy = sigmoidf_(rb[(16 + h*32 + p*2 + 1)*L_]);
        float gx = fminf(fmaxf(cx - 0.5f*sx + ox*sx, 0.f), 1.f) * (float)(W_-1);
        float gy = fminf(fmaxf(cy - 0.5f*sy + oy*sy, 0.f), 1.f) * (float)(H_-1);
        float a = rb[(272 + h*16 + p)*L_];
        float m = a;
        #pragma unroll
        for (int dd = 8; dd >= 1; dd >>= 1) m = fmaxf(m, __shfl_xor(m, dd, 16));
        float e = expf(a - m);
        float s = e;
        #pragma unroll
        for (int dd = 8; dd >= 1; dd >>= 1) s += __shfl_xor(s, dd, 16);
        float aw = e / s;
        float x0f = floorf(gx), y0f = floorf(gy);
        int x0 = (int)x0f, y0 = (int)y0f;
        const float wx = gx - x0f, wy = gy - y0f;
        const int o00 = (y0*W_ + x0) * (HD_*2);           // byte offset of cell00
        const int dxb = (x0 < W_-1) ? (HD_*2) : 0;        // +1 col (64 B) if valid
        const int dyb = (y0 < H_-1) ? (W_*HD_*2) : 0;     // +1 row if valid
        const float aiy = aw * (1.f - wy), awy = aw * wy;
        tblo[lsub][p] = make_int4(o00, o00 + dxb, o00 + dyb, o00 + dxb + dyb);
        tblw[lsub][p] = make_float4(aiy * (1.f - wx), aiy * wx,
                                    awy * (1.f - wx), awy * wx);
    }
    __syncthreads();

    // ---- main: gather + weighted combine ----
    const int wave = tid >> 6, lane = tid & 63;
    const int d2 = lane & 15;            // covers d = 2*d2, 2*d2+1
    const int pg = lane >> 4;            // 0..3, points p = pg*4 + pi
    const int d2b = d2 * 4;              // byte offset within cell
    const char* vbytes = (const char*)(memT + (size_t)(b*NH_ + h) * L_ * HD_);

    #pragma unroll
    for (int li = 0; li < 4; ++li) {
        const int lsub = wave*4 + li;
        uint u[16];
        float wcl[16];
        #pragma unroll
        for (int pi = 0; pi < 4; ++pi) {
            const int4   ob = tblo[lsub][pg*4 + pi];
            const float4 wv = tblw[lsub][pg*4 + pi];
            u[pi*4+0] = *(const uint*)(vbytes + (uint)(ob.x + d2b));
            u[pi*4+1] = *(const uint*)(vbytes + (uint)(ob.y + d2b));
            u[pi*4+2] = *(const uint*)(vbytes + (uint)(ob.z + d2b));
            u[pi*4+3] = *(const uint*)(vbytes + (uint)(ob.w + d2b));
            wcl[pi*4+0] = wv.x; wcl[pi*4+1] = wv.y;
            wcl[pi*4+2] = wv.z; wcl[pi*4+3] = wv.w;
        }
        f32x2 acc = {0.f, 0.f};
        #pragma unroll
        for (int k = 0; k < 16; ++k) {
            f32x2 v = { __uint_as_float(u[k] << 16), __uint_as_float(u[k] & 0xffff0000u) };
            acc += v * wcl[k];
        }
        acc.x += __shfl_xor(acc.x, 16);
        acc.y += __shfl_xor(acc.y, 16);
        acc.x += __shfl_xor(acc.x, 32);
        acc.y += __shfl_xor(acc.y, 32);
        if (pg == 0) { tile[lsub][d2*2] = acc.x; tile[lsub][d2*2+1] = acc.y; }
    }
    __syncthreads();
    if (tid < 128) {
        const int l = tid >> 3;
        const int c4 = (tid & 7) * 4;
        ushort4 v;
        v.x = f2bf(tile[l][c4+0]); v.y = f2bf(tile[l][c4+1]);
        v.z = f2bf(tile[l][c4+2]); v.w = f2bf(tile[l][c4+3]);
        *(ushort4*)(midT + ((size_t)(b*L_ + l0 + l))*C_ + h*HD_ + c4) = v;
    }
}

// GEMM-B (MFMA), 64x64 tile, 128 threads / 2 waves, 768 blocks (3/CU).
// out[b,o,l] = BN( sum_c w_out[o,c] * midT[b,l,c] )
__global__ __launch_bounds__(128) void gemm_b_mfma(const unsigned short* __restrict__ midT,
        const unsigned short* __restrict__ woutbf,
        const float* __restrict__ gamma, const float* __restrict__ beta,
        const float* __restrict__ mean, const float* __restrict__ var,
        float* __restrict__ out) {
    __shared__ short As[64 * LDK];
    __shared__ short Bs[64 * LDK];
    const int gid = blockIdx.x;          // 768 = 8 XCD * 96
    const int xcd = gid & 7, jj = gid >> 3;   // jj 0..95
    const int yt = xcd * 24 + jj / 4;    // n-tile 0..191 (contiguous l per XCD)
    const int xt = jj & 3;               // m-tile 0..3
    const int m0 = xt * 64;
    const int n0 = yt * 64;
    const int b  = n0 / L_, l0 = n0 % L_;
    const int tid = threadIdx.x;
    const int wave = tid >> 6, lane = tid & 63;
    const int fr = lane & 15, fg = lane >> 4;
    f32x4 acc[2][4] = {};

    const unsigned short* mT = midT + ((size_t)(b*L_ + l0)) * C_;
    const int sr = tid >> 1;
    const int sko = (tid & 1) * 32;

    for (int k0 = 0; k0 < C_; k0 += 64) {
        const short8* ga = (const short8*)(woutbf + (size_t)(m0 + sr)*C_ + k0 + sko);
        const short8* gb = (const short8*)(mT + (size_t)sr*C_ + k0 + sko);
        short* la = As + sr*LDK + sko;
        short* lb = Bs + sr*LDK + sko;
        #pragma unroll
        for (int q = 0; q < 4; ++q) {
            *(short8*)(la + q*8) = ga[q];
            *(short8*)(lb + q*8) = gb[q];
        }
        __syncthreads();
        #pragma unroll
        for (int kk = 0; kk < 64; kk += 32) {
            short8 af[2], bfm[4];
            #pragma unroll
            for (int m = 0; m < 2; ++m)
                af[m] = *(const short8*)(As + (wave*32 + m*16 + fr)*LDK + kk + fg*8);
            #pragma unroll
            for (int n = 0; n < 4; ++n)
                bfm[n] = *(const short8*)(Bs + (n*16 + fr)*LDK + kk + fg*8);
            #pragma unroll
            for (int m = 0; m < 2; ++m)
                #pragma unroll
                for (int n = 0; n < 4; ++n)
                    acc[m][n] = __builtin_amdgcn_mfma_f32_16x16x32_bf16(af[m], bfm[n], acc[m][n], 0, 0, 0);
        }
        __syncthreads();
    }

    #pragma unroll
    for (int m = 0; m < 2; ++m) {
        const int ob = m0 + wave*32 + m*16 + fg*4;
        float sc[4], mn[4], bt[4];
        #pragma unroll
        for (int q = 0; q < 4; ++q) {
            const int o = ob + q;
            sc[q] = gamma[o] * rsqrtf(var[o] + 1e-5f);
            mn[q] = mean[o]; bt[q] = beta[o];
        }
        #pragma unroll
        for (int n = 0; n < 4; ++n) {
            const int l = l0 + n*16 + fr;
            #pragma unroll
            for (int q = 0; q < 4; ++q)
                out[(size_t)b*C_*L_ + (size_t)(ob+q)*L_ + l] = (acc[m][n][q] - mn[q])*sc[q] + bt[q];
        }
    }
}

extern "C" void kernel_launch(void* const* d_in, const int* in_sizes, int n_in,
                              void* d_out, int out_size, void* d_ws, size_t ws_size,
                              hipStream_t stream) {
    const float* feat     = (const float*)d_in[0];
    const float* w_size   = (const float*)d_in[1];
    const float* b_size   = (const float*)d_in[2];
    const float* w_anchor = (const float*)d_in[3];
    const float* b_anchor = (const float*)d_in[4];
    const float* w_value  = (const float*)d_in[5];
    const float* b_value  = (const float*)d_in[6];
    const float* w_att    = (const float*)d_in[7];
    const float* b_att    = (const float*)d_in[8];
    const float* w_out    = (const float*)d_in[9];
    const float* bn_gamma = (const float*)d_in[10];
    const float* bn_beta  = (const float*)d_in[11];
    const float* bn_mean  = (const float*)d_in[12];
    const float* bn_var   = (const float*)d_in[13];

    float* ws = (float*)d_ws;
    unsigned short* wallbf = (unsigned short*)(ws + OFF_WALLBF);
    float*          ball   = ws + OFF_BALL;
    unsigned short* woutbf = (unsigned short*)(ws + OFF_WOUTBF);
    unsigned short* featT  = (unsigned short*)(ws + OFF_FEATT);
    unsigned short* memT   = (unsigned short*)(ws + OFF_MEMT);
    float*          raw    = ws + OFF_RAW;
    unsigned short* midT   = (unsigned short*)(ws + OFF_MIDT);

    prep<<<dim3(CO_PAD + C_ + (L_/32)*8*B_), dim3(256), 0, stream>>>(
        w_value, b_value, w_size, b_size, w_anchor, b_anchor, w_att, b_att,
        w_out, feat, wallbf, ball, woutbf, featT);
    gemm_a_mfma<<<dim3(8*288), dim3(128), 0, stream>>>(featT, wallbf, ball, memT, raw);
    sample_kernel<<<dim3(B_*NH_*(L_/16)), dim3(256), 0, stream>>>(memT, raw, midT);
    gemm_b_mfma<<<dim3(8*96), dim3(128), 0, stream>>>(
        midT, woutbf, bn_gamma, bn_beta, bn_mean, bn_var, (float*)d_out);
}

// Round 17
// 56.995 us; speedup vs baseline: 1.2524x; 1.1011x over previous
//
#include <hip/hip_runtime.h>
#include <math.h>

#define B_ 2
#define C_ 256
#define H_ 64
#define W_ 96
#define L_ (H_*W_)          // 6144
#define NH_ 8
#define NP_ 16
#define HD_ 32
#define NTOT (B_*L_)        // 12288
#define CO_ALL 656
#define CO_PAD 768
#define RAW_CH 400

typedef __attribute__((ext_vector_type(8))) short short8;
typedef __attribute__((ext_vector_type(4))) float f32x4;
typedef __attribute__((ext_vector_type(2))) float f32x2;

// global->LDS async staging, 16B per lane (dest = uniform base + lane*16)
#define GLOAD_LDS16(src, dst) __builtin_amdgcn_global_load_lds( \
    (const __attribute__((address_space(1))) void*)(src), \
    (__attribute__((address_space(3))) void*)(dst), 16, 0, 0)

// ---- workspace layout (float offsets) ----
#define OFF_WALLBF 0          // 768*256 ushort = 98304 floats
#define OFF_BALL   98304      // 768 floats -> 99072
#define OFF_WOUTBF 99072      // 256*256 ushort = 32768 floats -> 131840
#define OFF_FEATT  131840     // B*L*C ushort = 1572864 floats -> 1704704
#define OFF_MEMT   1704704    // B*NH*L*HD ushort = 1572864 floats -> 3277568
#define OFF_RAW    3277568    // B*400*L floats = 4915200 -> 8192768
#define OFF_MIDT   8192768    // B*L*C ushort = 1572864 floats -> 9765632 (~39.1 MB)

__device__ __forceinline__ float sigmoidf_(float x) { return 1.f / (1.f + expf(-x)); }

__device__ __forceinline__ unsigned short f2bf(float x) {
    union { float f; unsigned int u; } v; v.f = x;
    unsigned int r = (v.u + 0x7fffu + ((v.u >> 16) & 1u)) >> 16;
    return (unsigned short)r;
}

// Fused prep: blocks [0, CO_PAD+C_) pack weights to bf16; remaining 3072 blocks
// transpose feat[b][c][l] f32 -> featT[b][l][c] bf16 (32x32 LDS tiles).
__global__ __launch_bounds__(256) void prep(
        const float* __restrict__ wv, const float* __restrict__ bv,
        const float* __restrict__ wsz, const float* __restrict__ bsz,
        const float* __restrict__ wan, const float* __restrict__ ban,
        const float* __restrict__ wat, const float* __restrict__ bat,
        const float* __restrict__ wout, const float* __restrict__ feat,
        unsigned short* __restrict__ wallbf, float* __restrict__ ball,
        unsigned short* __restrict__ woutbf, unsigned short* __restrict__ featT) {
    __shared__ unsigned short tile[32][36];
    const int bid = blockIdx.x;
    const int t = threadIdx.x;
    if (bid < CO_PAD + C_) {
        const int o = bid, c = t;
        if (o < CO_PAD) {
            float v = 0.f, bvv = 0.f;
            if (o < 256)      { v = wv [(size_t)o*C_ + c];        bvv = bv [o]; }
            else if (o < 272) { v = wsz[(size_t)(o-256)*C_ + c];  bvv = bsz[o-256]; }
            else if (o < 528) { v = wan[(size_t)(o-272)*C_ + c];  bvv = ban[o-272]; }
            else if (o < 656) { v = wat[(size_t)(o-528)*C_ + c];  bvv = bat[o-528]; }
            wallbf[(size_t)o*C_ + c] = f2bf(v);
            if (c == 0) ball[o] = (o < CO_ALL) ? bvv : 0.f;
        } else {
            int r = o - CO_PAD;
            woutbf[(size_t)r*C_ + c] = f2bf(wout[(size_t)r*C_ + c]);
        }
        return;
    }
    const int tt = bid - (CO_PAD + C_);          // 0..3071
    const int l0 = (tt % (L_/32)) * 32;
    const int c0 = ((tt / (L_/32)) & 7) * 32;
    const int b  = tt / ((L_/32) * 8);
    {
        const int c = t >> 3, l4 = (t & 7) * 4;
        float4 v = *(const float4*)(feat + ((size_t)b*C_ + c0 + c)*L_ + l0 + l4);
        tile[c][l4+0] = f2bf(v.x); tile[c][l4+1] = f2bf(v.y);
        tile[c][l4+2] = f2bf(v.z); tile[c][l4+3] = f2bf(v.w);
    }
    __syncthreads();
    {
        const int l = t >> 3, c4 = (t & 7) * 4;
        ushort4 v;
        v.x = tile[c4+0][l]; v.y = tile[c4+1][l];
        v.z = tile[c4+2][l]; v.w = tile[c4+3][l];
        *(ushort4*)(featT + ((size_t)(b*L_ + l0 + l))*C_ + c0 + c4) = v;
    }
}

// GEMM-A (MFMA), 64x64 tile, 128 threads / 2 waves, 2304 blocks (9/CU).
// Staging via global_load_lds w16; linear LDS rows of 128B, XOR-swizzled chunks:
// LDS[r][c] holds global chunk c^(r&7); reads use chunk (kk/8+fg)^(r&7).
__global__ __launch_bounds__(128) void gemm_a_mfma(const unsigned short* __restrict__ featT,
        const unsigned short* __restrict__ wallbf, const float* __restrict__ ball,
        unsigned short* __restrict__ memT, float* __restrict__ raw) {
    __shared__ short As[64 * 64];
    __shared__ short Bs[64 * 64];
    const int gid = blockIdx.x;          // 2304 = 8 XCD * 288
    const int xcd = gid & 7, jj = gid >> 3;
    const int yt = xcd * 24 + jj / 12;
    const int xt = jj % 12;
    const int m0 = xt * 64;
    const int n0 = yt * 64;
    const int b  = n0 / L_, l0 = n0 % L_;
    const int tid = threadIdx.x;
    const int wave = tid >> 6, lane = tid & 63;
    const int fr = lane & 15, fg = lane >> 4;
    f32x4 acc[2][4] = {};

    const unsigned short* fT = featT + ((size_t)(b*L_ + l0)) * C_;
    const int lr = lane >> 3;            // row within 8-row staging group
    const int g8 = ((lane & 7) ^ lr) * 8; // swizzled source chunk (shorts)

    for (int k0 = 0; k0 < C_; k0 += 64) {
        if (wave == 0) {
            #pragma unroll
            for (int i = 0; i < 8; ++i) {
                const int r = i*8 + lr;
                GLOAD_LDS16(wallbf + (size_t)(m0 + r)*C_ + k0 + g8, As + i*512);
            }
        } else {
            #pragma unroll
            for (int i = 0; i < 8; ++i) {
                const int r = i*8 + lr;
                GLOAD_LDS16(fT + (size_t)r*C_ + k0 + g8, Bs + i*512);
            }
        }
        __syncthreads();
        #pragma unroll
        for (int kk = 0; kk < 64; kk += 32) {
            const int cb = (kk >> 3) + fg;   // base chunk 0..7
            short8 af[2], bfm[4];
            #pragma unroll
            for (int m = 0; m < 2; ++m) {
                const int r = wave*32 + m*16 + fr;
                af[m] = *(const short8*)(As + r*64 + (cb ^ (r & 7))*8);
            }
            #pragma unroll
            for (int n = 0; n < 4; ++n) {
                const int r = n*16 + fr;
                bfm[n] = *(const short8*)(Bs + r*64 + (cb ^ (r & 7))*8);
            }
            #pragma unroll
            for (int m = 0; m < 2; ++m)
                #pragma unroll
                for (int n = 0; n < 4; ++n)
                    acc[m][n] = __builtin_amdgcn_mfma_f32_16x16x32_bf16(af[m], bfm[n], acc[m][n], 0, 0, 0);
        }
        __syncthreads();
    }

    if (m0 < 256) {  // value path: memT[b][h][l][d] bf16
        #pragma unroll
        for (int m = 0; m < 2; ++m) {
            const int ob = m0 + wave*32 + m*16 + fg*4;
            const int h = ob >> 5, d0 = ob & 31;
            const float b0 = ball[ob], b1 = ball[ob+1], b2 = ball[ob+2], b3 = ball[ob+3];
            #pragma unroll
            for (int n = 0; n < 4; ++n) {
                const int l = l0 + n*16 + fr;
                ushort4 v;
                v.x = f2bf(acc[m][n][0] + b0);
                v.y = f2bf(acc[m][n][1] + b1);
                v.z = f2bf(acc[m][n][2] + b2);
                v.w = f2bf(acc[m][n][3] + b3);
                *(ushort4*)(memT + ((size_t)(b*NH_ + h)*L_ + l)*HD_ + d0) = v;
            }
        }
    } else {         // raw path: raw[b][r][l] f32
        #pragma unroll
        for (int m = 0; m < 2; ++m) {
            const int ob = m0 + wave*32 + m*16 + fg*4;
            #pragma unroll
            for (int n = 0; n < 4; ++n) {
                const int l = l0 + n*16 + fr;
                #pragma unroll
                for (int q = 0; q < 4; ++q) {
                    const int r = ob + q - 256;
                    if (r < RAW_CH)
                        raw[((size_t)(b*RAW_CH + r))*L_ + l] = acc[m][n][q] + ball[ob+q];
                }
            }
        }
    }
}

// Fused sampling (exact R11 structure — best verified).
__global__ __launch_bounds__(256) void sample_kernel(
        const unsigned short* __restrict__ memT,
        const float* __restrict__ raw,
        unsigned short* __restrict__ midT) {
    __shared__ int4   tblo[16][16];
    __shared__ float4 tblw[16][16];
    __shared__ float  tile[16][33];
    const int blk = blockIdx.x;          // 6144 = B_*NH_*(L_/16)
    const int xcd = blk & 7;
    const int j   = blk >> 3;
    const int half = (j >= 384) ? 1 : 0;
    const int bh  = xcd * 2 + half;
    const int lt  = j - half * 384;
    const int h = bh & 7;
    const int b = bh >> 3;
    const int l0 = lt * 16;
    const int tid = threadIdx.x;

    {
        const int p    = tid & 15;
        const int lsub = tid >> 4;
        const int l = l0 + lsub;
        const float* rb = raw + (size_t)b * RAW_CH * L_ + l;
        float sx = fminf(fmaxf(sigmoidf_(rb[(h*2+0)*L_]), 0.25f), 0.75f);
        float sy = fminf(fmaxf(sigmoidf_(rb[(h*2+1)*L_]), 0.25f), 0.75f);
        float cx = ((l % W_) + 0.5f) / ((float)W_ + 1e-6f);
        float cy = ((l / W_) + 0.5f) / ((float)H_ + 1e-6f);
        float ox = sigmoidf_(rb[(16 + h*32 + p*2 + 0)*L_]);
        float oy = sigmoidf_(rb[(16 + h*32 + p*2 + 1)*L_]);
        float gx = fminf(fmaxf(cx - 0.5f*sx + ox*sx, 0.f), 1.f) * (float)(W_-1);
        float gy = fminf(fmaxf(cy - 0.5f*sy + oy*sy, 0.f), 1.f) * (float)(H_-1);
        float a = rb[(272 + h*16 + p)*L_];
        float m = a;
        #pragma unroll
        for (int dd = 8; dd >= 1; dd >>= 1) m = fmaxf(m, __shfl_xor(m, dd, 16));
        float e = expf(a - m);
        float s = e;
        #pragma unroll
        for (int dd = 8; dd >= 1; dd >>= 1) s += __shfl_xor(s, dd, 16);
        float aw = e / s;
        float x0f = floorf(gx), y0f = floorf(gy);
        int x0 = (int)x0f, y0 = (int)y0f;
        const float wx = gx - x0f, wy = gy - y0f;
        const int o00 = (y0*W_ + x0) * (HD_*2);
        const int dxb = (x0 < W_-1) ? (HD_*2) : 0;
        const int dyb = (y0 < H_-1) ? (W_*HD_*2) : 0;
        const float aiy = aw * (1.f - wy), awy = aw * wy;
        tblo[lsub][p] = make_int4(o00, o00 + dxb, o00 + dyb, o00 + dxb + dyb);
        tblw[lsub][p] = make_float4(aiy * (1.f - wx), aiy * wx,
                                    awy * (1.f - wx), awy * wx);
    }
    __syncthreads();

    const int wave = tid >> 6, lane = tid & 63;
    const int d2 = lane & 15;
    const int pg = lane >> 4;
    const int d2b = d2 * 4;
    const char* vbytes = (const char*)(memT + (size_t)(b*NH_ + h) * L_ * HD_);

    #pragma unroll
    for (int li = 0; li < 4; ++li) {
        const int lsub = wave*4 + li;
        uint u[16];
        float wcl[16];
        #pragma unroll
        for (int pi = 0; pi < 4; ++pi) {
            const int4   ob = tblo[lsub][pg*4 + pi];
            const float4 wv = tblw[lsub][pg*4 + pi];
            u[pi*4+0] = *(const uint*)(vbytes + (uint)(ob.x + d2b));
            u[pi*4+1] = *(const uint*)(vbytes + (uint)(ob.y + d2b));
            u[pi*4+2] = *(const uint*)(vbytes + (uint)(ob.z + d2b));
            u[pi*4+3] = *(const uint*)(vbytes + (uint)(ob.w + d2b));
            wcl[pi*4+0] = wv.x; wcl[pi*4+1] = wv.y;
            wcl[pi*4+2] = wv.z; wcl[pi*4+3] = wv.w;
        }
        f32x2 acc = {0.f, 0.f};
        #pragma unroll
        for (int k = 0; k < 16; ++k) {
            f32x2 v = { __uint_as_float(u[k] << 16), __uint_as_float(u[k] & 0xffff0000u) };
            acc += v * wcl[k];
        }
        acc.x += __shfl_xor(acc.x, 16);
        acc.y += __shfl_xor(acc.y, 16);
        acc.x += __shfl_xor(acc.x, 32);
        acc.y += __shfl_xor(acc.y, 32);
        if (pg == 0) { tile[lsub][d2*2] = acc.x; tile[lsub][d2*2+1] = acc.y; }
    }
    __syncthreads();
    if (tid < 128) {
        const int l = tid >> 3;
        const int c4 = (tid & 7) * 4;
        ushort4 v;
        v.x = f2bf(tile[l][c4+0]); v.y = f2bf(tile[l][c4+1]);
        v.z = f2bf(tile[l][c4+2]); v.w = f2bf(tile[l][c4+3]);
        *(ushort4*)(midT + ((size_t)(b*L_ + l0 + l))*C_ + h*HD_ + c4) = v;
    }
}

// GEMM-B (MFMA), 64x64 tile, 128 threads / 2 waves, 768 blocks (3/CU).
// Same global_load_lds + swizzle staging as GEMM-A.
__global__ __launch_bounds__(128) void gemm_b_mfma(const unsigned short* __restrict__ midT,
        const unsigned short* __restrict__ woutbf,
        const float* __restrict__ gamma, const float* __restrict__ beta,
        const float* __restrict__ mean, const float* __restrict__ var,
        float* __restrict__ out) {
    __shared__ short As[64 * 64];
    __shared__ short Bs[64 * 64];
    const int gid = blockIdx.x;          // 768 = 8 XCD * 96
    const int xcd = gid & 7, jj = gid >> 3;
    const int yt = xcd * 24 + jj / 4;
    const int xt = jj & 3;
    const int m0 = xt * 64;
    const int n0 = yt * 64;
    const int b  = n0 / L_, l0 = n0 % L_;
    const int tid = threadIdx.x;
    const int wave = tid >> 6, lane = tid & 63;
    const int fr = lane & 15, fg = lane >> 4;
    f32x4 acc[2][4] = {};

    const unsigned short* mT = midT + ((size_t)(b*L_ + l0)) * C_;
    const int lr = lane >> 3;
    const int g8 = ((lane & 7) ^ lr) * 8;

    for (int k0 = 0; k0 < C_; k0 += 64) {
        if (wave == 0) {
            #pragma unroll
            for (int i = 0; i < 8; ++i) {
                const int r = i*8 + lr;
                GLOAD_LDS16(woutbf + (size_t)(m0 + r)*C_ + k0 + g8, As + i*512);
            }
        } else {
            #pragma unroll
            for (int i = 0; i < 8; ++i) {
                const int r = i*8 + lr;
                GLOAD_LDS16(mT + (size_t)r*C_ + k0 + g8, Bs + i*512);
            }
        }
        __syncthreads();
        #pragma unroll
        for (int kk = 0; kk < 64; kk += 32) {
            const int cb = (kk >> 3) + fg;
            short8 af[2], bfm[4];
            #pragma unroll
            for (int m = 0; m < 2; ++m) {
                const int r = wave*32 + m*16 + fr;
                af[m] = *(const short8*)(As + r*64 + (cb ^ (r & 7))*8);
            }
            #pragma unroll
            for (int n = 0; n < 4; ++n) {
                const int r = n*16 + fr;
                bfm[n] = *(const short8*)(Bs + r*64 + (cb ^ (r & 7))*8);
            }
            #pragma unroll
            for (int m = 0; m < 2; ++m)
                #pragma unroll
                for (int n = 0; n < 4; ++n)
                    acc[m][n] = __builtin_amdgcn_mfma_f32_16x16x32_bf16(af[m], bfm[n], acc[m][n], 0, 0, 0);
        }
        __syncthreads();
    }

    #pragma unroll
    for (int m = 0; m < 2; ++m) {
        const int ob = m0 + wave*32 + m*16 + fg*4;
        float sc[4], mn[4], bt[4];
        #pragma unroll
        for (int q = 0; q < 4; ++q) {
            const int o = ob + q;
            sc[q] = gamma[o] * rsqrtf(var[o] + 1e-5f);
            mn[q] = mean[o]; bt[q] = beta[o];
        }
        #pragma unroll
        for (int n = 0; n < 4; ++n) {
            const int l = l0 + n*16 + fr;
            #pragma unroll
            for (int q = 0; q < 4; ++q)
                out[(size_t)b*C_*L_ + (size_t)(ob+q)*L_ + l] = (acc[m][n][q] - mn[q])*sc[q] + bt[q];
        }
    }
}

extern "C" void kernel_launch(void* const* d_in, const int* in_sizes, int n_in,
                              void* d_out, int out_size, void* d_ws, size_t ws_size,
                              hipStream_t stream) {
    const float* feat     = (const float*)d_in[0];
    const float* w_size   = (const float*)d_in[1];
    const float* b_size   = (const float*)d_in[2];
    const float* w_anchor = (const float*)d_in[3];
    const float* b_anchor = (const float*)d_in[4];
    const float* w_value  = (const float*)d_in[5];
    const float* b_value  = (const float*)d_in[6];
    const float* w_att    = (const float*)d_in[7];
    const float* b_att    = (const float*)d_in[8];
    const float* w_out    = (const float*)d_in[9];
    const float* bn_gamma = (const float*)d_in[10];
    const float* bn_beta  = (const float*)d_in[11];
    const float* bn_mean  = (const float*)d_in[12];
    const float* bn_var   = (const float*)d_in[13];

    float* ws = (float*)d_ws;
    unsigned short* wallbf = (unsigned short*)(ws + OFF_WALLBF);
    float*          ball   = ws + OFF_BALL;
    unsigned short* woutbf = (unsigned short*)(ws + OFF_WOUTBF);
    unsigned short* featT  = (unsigned short*)(ws + OFF_FEATT);
    unsigned short* memT   = (unsigned short*)(ws + OFF_MEMT);
    float*          raw    = ws + OFF_RAW;
    unsigned short* midT   = (unsigned short*)(ws + OFF_MIDT);

    prep<<<dim3(CO_PAD + C_ + (L_/32)*8*B_), dim3(256), 0, stream>>>(
        w_value, b_value, w_size, b_size, w_anchor, b_anchor, w_att, b_att,
        w_out, feat, wallbf, ball, woutbf, featT);
    gemm_a_mfma<<<dim3(8*288), dim3(128), 0, stream>>>(featT, wallbf, ball, memT, raw);
    sample_kernel<<<dim3(B_*NH_*(L_/16)), dim3(256), 0, stream>>>(memT, raw, midT);
    gemm_b_mfma<<<dim3(8*96), dim3(128), 0, stream>>>(
        midT, woutbf, bn_gamma, bn_beta, bn_mean, bn_var, (float*)d_out);
}